// Round 7
// baseline (317.758 us; speedup 1.0000x reference)
//
#include <hip/hip_runtime.h>
#include <hip/hip_bf16.h>
#include <math.h>

#define B_   8
#define T_   2048
#define DIN  1024
#define H_   1024
#define G_   16
#define M_   (B_ * T_)   // 16384
#define NCH  (B_ * H_)   // 8192 channels
#define SUB  32          // timesteps per scan subchunk
#define NSUB (T_ / SUB)  // 64 subchunks per channel

#define LN2f     0.69314718056f
#define LOG2Ef   1.44269504089f

typedef __bf16 bf16_t;
typedef __bf16 bf16x8 __attribute__((ext_vector_type(8)));
typedef float  f32x4  __attribute__((ext_vector_type(4)));

__device__ __forceinline__ float bf2f(unsigned short u) {
    union { unsigned int i; float f; } c; c.i = ((unsigned int)u) << 16; return c.f;
}
__device__ __forceinline__ unsigned short f2bf(float f) {
    union { __bf16 h; unsigned short u; } c; c.h = (__bf16)f; return c.u;
}
__device__ __forceinline__ float fexp2(float x) { return __builtin_amdgcn_exp2f(x); }
__device__ __forceinline__ float flog2(float x) { return __builtin_amdgcn_logf(x); }

__device__ __forceinline__ float log_g_dev(float x) {
    return (x >= 0.f) ? LN2f * flog2(x + 0.5f)
                      : (x - LN2f * flog2(1.f + fexp2(x * LOG2Ef)));
}
__device__ __forceinline__ float logaddexp_f(float a, float b) {
    float m = fmaxf(a, b);
    float d = -fabsf(a - b);                 // <= 0 (or -inf)
    return m + LN2f * flog2(1.f + fexp2(d * LOG2Ef));
}

// async global->LDS, 16 bytes per lane; LDS dest = uniform base + lane*16
__device__ __forceinline__ void async16(bf16_t* lds, const bf16_t* g) {
    __builtin_amdgcn_global_load_lds(
        (const __attribute__((address_space(1))) void*)g,
        (__attribute__((address_space(3))) void*)lds, 16, 0, 0);
}

// ---------------------------------------------------------------------------
// fp32 -> bf16 bulk convert for X, Wz, Wh in one launch (8 elems/thread).
// All region sizes are multiples of 256*8 -> branch is block-uniform.
// ---------------------------------------------------------------------------
#define NX8 (M_ * DIN / 8)
#define NW8 (H_ * DIN / 8)

__global__ __launch_bounds__(256) void cvt_all(
    const float* __restrict__ x,  bf16_t* __restrict__ Xb,
    const float* __restrict__ wz, bf16_t* __restrict__ Wzb,
    const float* __restrict__ wh, bf16_t* __restrict__ Whb)
{
    int i = blockIdx.x * 256 + threadIdx.x;
    const float* src; bf16_t* dst;
    if (i < NX8)            { src = x;  dst = Xb; }
    else if (i < NX8 + NW8) { src = wz; dst = Wzb; i -= NX8; }
    else                    { src = wh; dst = Whb; i -= NX8 + NW8; }
    float4 a = ((const float4*)src)[2 * i];
    float4 b = ((const float4*)src)[2 * i + 1];
    bf16x8 o = {(__bf16)a.x, (__bf16)a.y, (__bf16)a.z, (__bf16)a.w,
                (__bf16)b.x, (__bf16)b.y, (__bf16)b.z, (__bf16)b.w};
    ((bf16x8*)dst)[i] = o;
}

// ---------------------------------------------------------------------------
// bf16 MFMA GEMM, 128x64 block tile, BK=64 (16 iters), wave 64x32 per matrix.
// Fused epilogue: Cb = raw -softplus(k) (bf16), Vb = -softplus(-k)+log_g(q),
// plus in-block group-norm: BN==64 == one group -> nrm(row,g) -> Nbuf [M,16].
// LDS chunk layout: 16B chunk (mt*128 + kq*16 + row): kq = ks*4 + (lane>>4).
// ---------------------------------------------------------------------------
#define BM 128
#define BN 64
#define BK 64

__global__ __launch_bounds__(256, 4) void gemm_mfma(
    const bf16_t* __restrict__ Xb,
    const bf16_t* __restrict__ Wzb, const float* __restrict__ bz,
    const bf16_t* __restrict__ Whb, const float* __restrict__ bh,
    bf16_t* __restrict__ Cb, bf16_t* __restrict__ Vb,
    float* __restrict__ Nbuf)
{
    __shared__ bf16_t sA[BM * BK];   // 16 KB, 8 m-tiles
    __shared__ bf16_t sZ[BN * BK];   //  8 KB, 4 n-tiles
    __shared__ bf16_t sH[BN * BK];   //  8 KB
    __shared__ float  sN[2][BM];     //  1 KB  [wn][rowInBlock]

    const int tid  = threadIdx.x;
    const int m0   = blockIdx.x * BM;
    const int n0   = blockIdx.y * BN;
    const int lane = tid & 63;
    const int wave = tid >> 6;
    const int wm = wave & 1, wn = wave >> 1;   // wave tile: rows wm*64, cols wn*32

    const int srow = lane & 15;
    const int scol = (lane >> 4) * 8;
    // A: wave stages m-tiles wave*2, wave*2+1 (2 k-halves each)
    const size_t gA0 = (size_t)(m0 + wave * 32      + srow) * DIN + scol;
    const size_t gA1 = (size_t)(m0 + wave * 32 + 16 + srow) * DIN + scol;
    // Z/H: wave stages n-tile `wave` (2 k-halves each)
    const size_t gB0 = (size_t)(n0 + wave * 16      + srow) * DIN + scol;
    bf16_t* lA0 = sA + (wave * 2    ) * 1024;
    bf16_t* lA1 = sA + (wave * 2 + 1) * 1024;
    bf16_t* lZ0 = sZ + wave * 1024;
    bf16_t* lH0 = sH + wave * 1024;

    f32x4 dz[4][2], dh[4][2];
    #pragma unroll
    for (int i = 0; i < 4; ++i)
        #pragma unroll
        for (int j = 0; j < 2; ++j) { dz[i][j] = (f32x4)0.f; dh[i][j] = (f32x4)0.f; }

    for (int k0 = 0; k0 < DIN; k0 += BK) {
        __syncthreads();                         // prev tile's LDS reads done
        async16(lA0,       Xb  + gA0 + k0);
        async16(lA0 + 512, Xb  + gA0 + k0 + 32);
        async16(lA1,       Xb  + gA1 + k0);
        async16(lA1 + 512, Xb  + gA1 + k0 + 32);
        async16(lZ0,       Wzb + gB0 + k0);
        async16(lZ0 + 512, Wzb + gB0 + k0 + 32);
        async16(lH0,       Whb + gB0 + k0);
        async16(lH0 + 512, Whb + gB0 + k0 + 32);
        __syncthreads();                         // vmcnt(0) drain + barrier

        #pragma unroll
        for (int ks = 0; ks < 2; ++ks) {
            bf16x8 af[4], bzf[2], bhf[2];
            #pragma unroll
            for (int i = 0; i < 4; ++i)
                af[i] = *(bf16x8*)(sA + ((wm * 4 + i) * 128 + ks * 64 + lane) * 8);
            #pragma unroll
            for (int j = 0; j < 2; ++j) {
                bzf[j] = *(bf16x8*)(sZ + ((wn * 2 + j) * 128 + ks * 64 + lane) * 8);
                bhf[j] = *(bf16x8*)(sH + ((wn * 2 + j) * 128 + ks * 64 + lane) * 8);
            }
            #pragma unroll
            for (int i = 0; i < 4; ++i)
                #pragma unroll
                for (int j = 0; j < 2; ++j) {
                    dz[i][j] = __builtin_amdgcn_mfma_f32_16x16x32_bf16(af[i], bzf[j], dz[i][j], 0, 0, 0);
                    dh[i][j] = __builtin_amdgcn_mfma_f32_16x16x32_bf16(af[i], bhf[j], dh[i][j], 0, 0, 0);
                }
        }
    }

    // ---- epilogue: D layout col = lane&15, row = (lane>>4)*4 + reg ----
    const int cq = lane >> 4;
    const int cn = lane & 15;
    float ss[4][4];                      // per-(i,rr) sum over this lane's cols
    #pragma unroll
    for (int i = 0; i < 4; ++i)
        #pragma unroll
        for (int rr = 0; rr < 4; ++rr) ss[i][rr] = 0.f;

    #pragma unroll
    for (int j = 0; j < 2; ++j) {
        const int col = n0 + (wn * 2 + j) * 16 + cn;
        const float bzv = bz[col];
        const float bhv = bh[col];
        #pragma unroll
        for (int i = 0; i < 4; ++i) {
            const int row0 = m0 + (wm * 4 + i) * 16 + cq * 4;
            #pragma unroll
            for (int rr = 0; rr < 4; ++rr) {
                float k = dz[i][j][rr] + bzv;
                float q = dh[i][j][rr] + bhv;
                float t   = LN2f * flog2(1.f + fexp2(-fabsf(k) * LOG2Ef));
                float lz  = fminf(k, 0.f) - t;
                float lc0 = -fmaxf(k, 0.f) - t;
                ss[i][rr] += lc0 * lc0;
                size_t off = (size_t)(row0 + rr) * H_ + col;
                ((unsigned short*)Cb)[off] = f2bf(lc0);
                ((unsigned short*)Vb)[off] = f2bf(lz + log_g_dev(q));
            }
        }
    }

    // reduce ss over the 16 cn-lanes (bits 0..3 of lane)
    #pragma unroll
    for (int i = 0; i < 4; ++i)
        #pragma unroll
        for (int rr = 0; rr < 4; ++rr) {
            float v = ss[i][rr];
            v += __shfl_xor(v, 1);
            v += __shfl_xor(v, 2);
            v += __shfl_xor(v, 4);
            v += __shfl_xor(v, 8);
            ss[i][rr] = v;
        }
    __syncthreads();                 // main-loop LDS use finished everywhere
    if (cn == 0) {
        #pragma unroll
        for (int i = 0; i < 4; ++i)
            #pragma unroll
            for (int rr = 0; rr < 4; ++rr)
                sN[wn][wm * 64 + i * 16 + cq * 4 + rr] = ss[i][rr];
    }
    __syncthreads();
    if (tid < BM) {
        float nrm = sqrtf(sN[0][tid] + sN[1][tid]);
        Nbuf[(size_t)(m0 + tid) * G_ + blockIdx.y] = nrm;
    }
}

// ---------------------------------------------------------------------------
// fac = (nrm - logsumexp_g(nrm)) / nrm, in place on Nbuf. One thread per row.
// ---------------------------------------------------------------------------
__global__ __launch_bounds__(256) void fack(float* __restrict__ Nbuf)
{
    const int row = blockIdx.x * 256 + threadIdx.x;   // 0..M-1
    float4 n4[4];
    #pragma unroll
    for (int q = 0; q < 4; ++q) n4[q] = ((float4*)(Nbuf + (size_t)row * G_))[q];
    float* n = (float*)n4;
    float mx = n[0];
    #pragma unroll
    for (int g = 1; g < G_; ++g) mx = fmaxf(mx, n[g]);
    float se = 0.f;
    #pragma unroll
    for (int g = 0; g < G_; ++g) se += fexp2((n[g] - mx) * LOG2Ef);
    const float lse = mx + LN2f * flog2(se);
    #pragma unroll
    for (int g = 0; g < G_; ++g) n[g] = (n[g] - lse) / n[g];
    #pragma unroll
    for (int q = 0; q < 4; ++q) ((float4*)(Nbuf + (size_t)row * G_))[q] = n4[q];
}

// ---------------------------------------------------------------------------
// Chunked parallel scan, 3 phases; c_t = lc0_t * fac(b,t,g) applied on the fly
// (each wave covers one 64-aligned h block == exactly one group g).
// ---------------------------------------------------------------------------
__global__ __launch_bounds__(256) void scan_sum(
    const bf16_t* __restrict__ Cb, const bf16_t* __restrict__ Vb,
    const float* __restrict__ Fac, float2* __restrict__ Sb)
{
    const int hl   = threadIdx.x & 63;
    const int ssub = threadIdx.x >> 6;                  // 0..3
    const int ch   = blockIdx.x * 64 + hl;              // 0..8191
    const int subg = blockIdx.y * 4 + ssub;             // 0..63
    const int b = ch >> 10, h = ch & 1023;
    const int g = h >> 6;

    size_t idx = ((size_t)b * T_ + (size_t)subg * SUB) * H_ + h;
    const float* fp = Fac + (size_t)(b * T_ + subg * SUB) * G_ + g;
    float A = 0.f, Bv = -INFINITY;
    #pragma unroll 4
    for (int s = 0; s < SUB; ++s) {
        float c = bf2f(((const unsigned short*)Cb)[idx]) * fp[s * G_];
        float v = bf2f(((const unsigned short*)Vb)[idx]);
        A += c;
        Bv = logaddexp_f(Bv + c, v);
        idx += H_;
    }
    float2 o; o.x = A; o.y = Bv;
    Sb[(size_t)subg * NCH + ch] = o;
}

__global__ __launch_bounds__(256) void scan_mid(
    float2* __restrict__ Sb, const float* __restrict__ h0)
{
    const int ch = blockIdx.x * 256 + threadIdx.x;      // 0..8191
    float s = log_g_dev(h0[ch]);
    for (int k = 0; k < NSUB; ++k) {
        float2 ab = Sb[(size_t)k * NCH + ch];
        float snew = logaddexp_f(s + ab.x, ab.y);
        Sb[(size_t)k * NCH + ch].x = s;    // seed (incoming state) for subchunk k
        s = snew;
    }
}

__global__ __launch_bounds__(256) void scan_out(
    const bf16_t* __restrict__ Cb, bf16_t* Vb /* == d_out */,
    const float* __restrict__ Fac, const float2* __restrict__ Sb)
{
    const int hl   = threadIdx.x & 63;
    const int ssub = threadIdx.x >> 6;
    const int ch   = blockIdx.x * 64 + hl;
    const int subg = blockIdx.y * 4 + ssub;
    const int b = ch >> 10, h = ch & 1023;
    const int g = h >> 6;

    float s = Sb[(size_t)subg * NCH + ch].x;
    size_t idx = ((size_t)b * T_ + (size_t)subg * SUB) * H_ + h;
    const float* fp = Fac + (size_t)(b * T_ + subg * SUB) * G_ + g;
    #pragma unroll 4
    for (int t = 0; t < SUB; ++t) {
        float c = bf2f(((const unsigned short*)Cb)[idx]) * fp[t * G_];
        float v = bf2f(((const unsigned short*)Vb)[idx]);
        s = logaddexp_f(s + c, v);
        float out = fexp2(fminf(s, 88.f) * LOG2Ef);  // finite, <= 1.7e38
        ((unsigned short*)Vb)[idx] = f2bf(out);
        idx += H_;
    }
}

// ---------------------------------------------------------------------------
extern "C" void kernel_launch(void* const* d_in, const int* in_sizes, int n_in,
                              void* d_out, int out_size, void* d_ws, size_t ws_size,
                              hipStream_t stream)
{
    const float* x   = (const float*)d_in[0];
    const float* h0  = (const float*)d_in[1];
    const float* Wz  = (const float*)d_in[2];
    const float* bz  = (const float*)d_in[3];
    const float* Wh  = (const float*)d_in[4];
    const float* bh  = (const float*)d_in[5];

    bf16_t* out = (bf16_t*)d_out;                                 // [B,T,H] bf16
    char*   ws  = (char*)d_ws;
    bf16_t* Cb  = (bf16_t*)ws;                                    // 33.5 MB raw lc0
    float2* Sb  = (float2*)(ws + (size_t)M_ * H_ * 2);            //  4.0 MB
    bf16_t* Xb  = (bf16_t*)((char*)Sb + (size_t)NSUB * NCH * 8);  // 33.5 MB
    bf16_t* Wzb = Xb + (size_t)M_ * DIN;                          //  2.0 MB
    bf16_t* Whb = Wzb + (size_t)H_ * DIN;                         //  2.0 MB
    float*  Nb  = (float*)(Whb + (size_t)H_ * DIN);               //  1.0 MB norms->fac

    cvt_all<<<NX8 / 256 + 2 * (NW8 / 256), 256, 0, stream>>>(x, Xb, Wz, Wzb, Wh, Whb);
    gemm_mfma<<<dim3(M_ / BM, H_ / BN), 256, 0, stream>>>(Xb, Wzb, bz, Whb, bh, Cb, out, Nb);
    fack<<<M_ / 256, 256, 0, stream>>>(Nb);
    scan_sum<<<dim3(NCH / 64, NSUB / 4), 256, 0, stream>>>(Cb, out, Nb, Sb);
    scan_mid<<<NCH / 256, 256, 0, stream>>>(Sb, h0);
    scan_out<<<dim3(NCH / 64, NSUB / 4), 256, 0, stream>>>(Cb, out, Nb, Sb);
}

// Round 8
// 298.847 us; speedup vs baseline: 1.0633x; 1.0633x over previous
//
#include <hip/hip_runtime.h>
#include <hip/hip_bf16.h>
#include <math.h>

#define B_   8
#define T_   2048
#define DIN  1024
#define H_   1024
#define G_   16
#define M_   (B_ * T_)   // 16384
#define NCH  (B_ * H_)   // 8192 channels
#define SUB  32          // timesteps per scan subchunk
#define NSUB (T_ / SUB)  // 64 subchunks per channel

#define LN2f     0.69314718056f
#define LOG2Ef   1.44269504089f

typedef __bf16 bf16_t;
typedef __bf16 bf16x8 __attribute__((ext_vector_type(8)));
typedef float  f32x4  __attribute__((ext_vector_type(4)));
typedef unsigned short u16x8 __attribute__((ext_vector_type(8)));

__device__ __forceinline__ float bf2f(unsigned short u) {
    union { unsigned int i; float f; } c; c.i = ((unsigned int)u) << 16; return c.f;
}
__device__ __forceinline__ unsigned short f2bf(float f) {
    union { __bf16 h; unsigned short u; } c; c.h = (__bf16)f; return c.u;
}
__device__ __forceinline__ float fexp2(float x) { return __builtin_amdgcn_exp2f(x); }
__device__ __forceinline__ float flog2(float x) { return __builtin_amdgcn_logf(x); }

__device__ __forceinline__ float log_g_dev(float x) {
    return (x >= 0.f) ? LN2f * flog2(x + 0.5f)
                      : (x - LN2f * flog2(1.f + fexp2(x * LOG2Ef)));
}
__device__ __forceinline__ float logaddexp_f(float a, float b) {
    float m = fmaxf(a, b);
    float d = -fabsf(a - b);                 // <= 0 (or -inf)
    return m + LN2f * flog2(1.f + fexp2(d * LOG2Ef));
}

// async global->LDS, 16 bytes per lane; LDS dest = uniform base + lane*16
__device__ __forceinline__ void async16(bf16_t* lds, const bf16_t* g) {
    __builtin_amdgcn_global_load_lds(
        (const __attribute__((address_space(1))) void*)g,
        (__attribute__((address_space(3))) void*)lds, 16, 0, 0);
}

// ---------------------------------------------------------------------------
// fp32 -> bf16 bulk convert for X, Wz, Wh in one launch (8 elems/thread).
// ---------------------------------------------------------------------------
#define NX8 (M_ * DIN / 8)
#define NW8 (H_ * DIN / 8)

__global__ __launch_bounds__(256) void cvt_all(
    const float* __restrict__ x,  bf16_t* __restrict__ Xb,
    const float* __restrict__ wz, bf16_t* __restrict__ Wzb,
    const float* __restrict__ wh, bf16_t* __restrict__ Whb)
{
    int i = blockIdx.x * 256 + threadIdx.x;
    const float* src; bf16_t* dst;
    if (i < NX8)            { src = x;  dst = Xb; }
    else if (i < NX8 + NW8) { src = wz; dst = Wzb; i -= NX8; }
    else                    { src = wh; dst = Whb; i -= NX8 + NW8; }
    float4 a = ((const float4*)src)[2 * i];
    float4 b = ((const float4*)src)[2 * i + 1];
    bf16x8 o = {(__bf16)a.x, (__bf16)a.y, (__bf16)a.z, (__bf16)a.w,
                (__bf16)b.x, (__bf16)b.y, (__bf16)b.z, (__bf16)b.w};
    ((bf16x8*)dst)[i] = o;
}

// ---------------------------------------------------------------------------
// bf16 MFMA GEMM, 128x64 block tile, BK=32, wave tile 64x32 per matrix.
// Fused epilogue with LDS-transposed COALESCED stores (16B/lane) and
// in-block group-norm (BN == 64 == one group): nrm(row,g) -> Nbuf [M,16].
//   Cb = raw -softplus(k) (bf16) ; Vb = -softplus(-k) + log_g(q) (bf16, d_out)
// ---------------------------------------------------------------------------
#define BM 128
#define BN 64
#define BK 32
#define STRD 72   // LDS transpose stride (elems): 144B rows -> 16B aligned

__global__ __launch_bounds__(256, 4) void gemm_mfma(
    const bf16_t* __restrict__ Xb,
    const bf16_t* __restrict__ Wzb, const float* __restrict__ bz,
    const bf16_t* __restrict__ Whb, const float* __restrict__ bh,
    bf16_t* __restrict__ Cb, bf16_t* __restrict__ Vb,
    float* __restrict__ Nbuf)
{
    __shared__ bf16_t sA[BM * BK];            //  8 KB
    __shared__ bf16_t sZ[BN * BK];            //  4 KB
    __shared__ bf16_t sH[BN * BK];            //  4 KB
    __shared__ float  sN[2][BM];              //  1 KB
    __shared__ unsigned short sT[BM * STRD];  // 18 KB output staging

    const int tid  = threadIdx.x;
    const int m0   = blockIdx.x * BM;
    const int n0   = blockIdx.y * BN;
    const int lane = tid & 63;
    const int wave = tid >> 6;
    const int wm = wave & 1, wn = wave >> 1;   // wave tile: rows wm*64, cols wn*32

    // staging: wave stages A m-tiles (wave*2, wave*2+1), Z/H n-tile (wave)
    const int srow = lane & 15;
    const int scol = (lane >> 4) * 8;
    const size_t gA0 = (size_t)(m0 + wave * 32      + srow) * DIN + scol;
    const size_t gA1 = (size_t)(m0 + wave * 32 + 16 + srow) * DIN + scol;
    const size_t gB0 = (size_t)(n0 + wave * 16      + srow) * DIN + scol;
    bf16_t* lA0 = sA + (wave * 2    ) * 512;
    bf16_t* lA1 = sA + (wave * 2 + 1) * 512;
    bf16_t* lZ0 = sZ + wave * 512;
    bf16_t* lH0 = sH + wave * 512;

    f32x4 dz[4][2], dh[4][2];
    #pragma unroll
    for (int i = 0; i < 4; ++i)
        #pragma unroll
        for (int j = 0; j < 2; ++j) { dz[i][j] = (f32x4)0.f; dh[i][j] = (f32x4)0.f; }

    for (int k0 = 0; k0 < DIN; k0 += BK) {
        __syncthreads();                         // prev tile's LDS reads done
        async16(lA0, Xb  + gA0 + k0);
        async16(lA1, Xb  + gA1 + k0);
        async16(lZ0, Wzb + gB0 + k0);
        async16(lH0, Whb + gB0 + k0);
        __syncthreads();                         // vmcnt(0) drain + barrier

        bf16x8 af[4], bzf[2], bhf[2];
        #pragma unroll
        for (int i = 0; i < 4; ++i)
            af[i] = *(bf16x8*)(sA + ((wm * 4 + i) * 64 + lane) * 8);
        #pragma unroll
        for (int j = 0; j < 2; ++j) {
            bzf[j] = *(bf16x8*)(sZ + ((wn * 2 + j) * 64 + lane) * 8);
            bhf[j] = *(bf16x8*)(sH + ((wn * 2 + j) * 64 + lane) * 8);
        }
        #pragma unroll
        for (int i = 0; i < 4; ++i)
            #pragma unroll
            for (int j = 0; j < 2; ++j) {
                dz[i][j] = __builtin_amdgcn_mfma_f32_16x16x32_bf16(af[i], bzf[j], dz[i][j], 0, 0, 0);
                dh[i][j] = __builtin_amdgcn_mfma_f32_16x16x32_bf16(af[i], bhf[j], dh[i][j], 0, 0, 0);
            }
    }

    // ---- epilogue. D layout: col = lane&15, row = (lane>>4)*4 + reg ----
    const int cq = lane >> 4;
    const int cn = lane & 15;
    float lc0v[2][4][4];
    float ssum[4][4];
    #pragma unroll
    for (int i = 0; i < 4; ++i)
        #pragma unroll
        for (int rr = 0; rr < 4; ++rr) ssum[i][rr] = 0.f;

    // compute; stage lv into sT (sT untouched by main loop -> no barrier yet)
    #pragma unroll
    for (int j = 0; j < 2; ++j) {
        const int col = wn * 32 + j * 16 + cn;          // 0..63 in block
        const float bzv = bz[n0 + col];
        const float bhv = bh[n0 + col];
        #pragma unroll
        for (int i = 0; i < 4; ++i) {
            const int lrow = wm * 64 + i * 16 + cq * 4; // 0..127 in block
            #pragma unroll
            for (int rr = 0; rr < 4; ++rr) {
                float k = dz[i][j][rr] + bzv;
                float q = dh[i][j][rr] + bhv;
                float t   = LN2f * flog2(1.f + fexp2(-fabsf(k) * LOG2Ef));
                float lz  = fminf(k, 0.f) - t;
                float lc0 = -fmaxf(k, 0.f) - t;
                lc0v[j][i][rr] = lc0;
                ssum[i][rr] += lc0 * lc0;
                sT[(lrow + rr) * STRD + col] = f2bf(lz + log_g_dev(q));
            }
        }
    }
    // group-norm partial: reduce over the 16 cn-lanes (lane bits 0..3)
    #pragma unroll
    for (int i = 0; i < 4; ++i)
        #pragma unroll
        for (int rr = 0; rr < 4; ++rr) {
            float v = ssum[i][rr];
            v += __shfl_xor(v, 1);
            v += __shfl_xor(v, 2);
            v += __shfl_xor(v, 4);
            v += __shfl_xor(v, 8);
            ssum[i][rr] = v;
        }
    if (cn == 0) {
        #pragma unroll
        for (int i = 0; i < 4; ++i)
            #pragma unroll
            for (int rr = 0; rr < 4; ++rr)
                sN[wn][wm * 64 + i * 16 + cq * 4 + rr] = ssum[i][rr];
    }
    __syncthreads();                 // sT(lv) + sN complete

    // coalesced V store (16B/lane) + Nbuf
    const int trow = tid >> 3;           // 0..31
    const int tc8  = (tid & 7) * 8;      // 0,8,..,56
    #pragma unroll
    for (int p = 0; p < 4; ++p) {
        const int row = p * 32 + trow;
        u16x8 v = *(const u16x8*)&sT[row * STRD + tc8];
        *(u16x8*)((unsigned short*)Vb + (size_t)(m0 + row) * H_ + n0 + tc8) = v;
    }
    if (tid < BM) {
        float nrm = sqrtf(sN[0][tid] + sN[1][tid]);
        Nbuf[(size_t)(m0 + tid) * G_ + blockIdx.y] = nrm;
    }
    __syncthreads();                 // sT reads done

    // stage lc0 and store Cb the same way
    #pragma unroll
    for (int j = 0; j < 2; ++j) {
        const int col = wn * 32 + j * 16 + cn;
        #pragma unroll
        for (int i = 0; i < 4; ++i) {
            const int lrow = wm * 64 + i * 16 + cq * 4;
            #pragma unroll
            for (int rr = 0; rr < 4; ++rr)
                sT[(lrow + rr) * STRD + col] = f2bf(lc0v[j][i][rr]);
        }
    }
    __syncthreads();
    #pragma unroll
    for (int p = 0; p < 4; ++p) {
        const int row = p * 32 + trow;
        u16x8 v = *(const u16x8*)&sT[row * STRD + tc8];
        *(u16x8*)((unsigned short*)Cb + (size_t)(m0 + row) * H_ + n0 + tc8) = v;
    }
}

// ---------------------------------------------------------------------------
// fac = (nrm - logsumexp_g(nrm)) / nrm, in place on Nbuf. One thread per row.
// ---------------------------------------------------------------------------
__global__ __launch_bounds__(256) void fack(float* __restrict__ Nbuf)
{
    const int row = blockIdx.x * 256 + threadIdx.x;   // 0..M-1
    float4 n4[4];
    #pragma unroll
    for (int q = 0; q < 4; ++q) n4[q] = ((float4*)(Nbuf + (size_t)row * G_))[q];
    float* n = (float*)n4;
    float mx = n[0];
    #pragma unroll
    for (int g = 1; g < G_; ++g) mx = fmaxf(mx, n[g]);
    float se = 0.f;
    #pragma unroll
    for (int g = 0; g < G_; ++g) se += fexp2((n[g] - mx) * LOG2Ef);
    const float lse = mx + LN2f * flog2(se);
    #pragma unroll
    for (int g = 0; g < G_; ++g) n[g] = (n[g] - lse) / n[g];
    #pragma unroll
    for (int q = 0; q < 4; ++q) ((float4*)(Nbuf + (size_t)row * G_))[q] = n4[q];
}

// ---------------------------------------------------------------------------
// Chunked parallel scan, 3 phases; c_t = lc0_t * fac(b,t,g) applied on the fly
// (each wave covers one 64-aligned h block == exactly one group g).
// ---------------------------------------------------------------------------
__global__ __launch_bounds__(256) void scan_sum(
    const bf16_t* __restrict__ Cb, const bf16_t* __restrict__ Vb,
    const float* __restrict__ Fac, float2* __restrict__ Sb)
{
    const int hl   = threadIdx.x & 63;
    const int ssub = threadIdx.x >> 6;                  // 0..3
    const int ch   = blockIdx.x * 64 + hl;              // 0..8191
    const int subg = blockIdx.y * 4 + ssub;             // 0..63
    const int b = ch >> 10, h = ch & 1023;
    const int g = h >> 6;

    size_t idx = ((size_t)b * T_ + (size_t)subg * SUB) * H_ + h;
    const float* fp = Fac + (size_t)(b * T_ + subg * SUB) * G_ + g;
    float A = 0.f, Bv = -INFINITY;
    #pragma unroll 4
    for (int s = 0; s < SUB; ++s) {
        float c = bf2f(((const unsigned short*)Cb)[idx]) * fp[s * G_];
        float v = bf2f(((const unsigned short*)Vb)[idx]);
        A += c;
        Bv = logaddexp_f(Bv + c, v);
        idx += H_;
    }
    float2 o; o.x = A; o.y = Bv;
    Sb[(size_t)subg * NCH + ch] = o;
}

__global__ __launch_bounds__(256) void scan_mid(
    float2* __restrict__ Sb, const float* __restrict__ h0)
{
    const int ch = blockIdx.x * 256 + threadIdx.x;      // 0..8191
    float s = log_g_dev(h0[ch]);
    for (int k = 0; k < NSUB; ++k) {
        float2 ab = Sb[(size_t)k * NCH + ch];
        float snew = logaddexp_f(s + ab.x, ab.y);
        Sb[(size_t)k * NCH + ch].x = s;    // seed (incoming state) for subchunk k
        s = snew;
    }
}

__global__ __launch_bounds__(256) void scan_out(
    const bf16_t* __restrict__ Cb, bf16_t* Vb /* == d_out */,
    const float* __restrict__ Fac, const float2* __restrict__ Sb)
{
    const int hl   = threadIdx.x & 63;
    const int ssub = threadIdx.x >> 6;
    const int ch   = blockIdx.x * 64 + hl;
    const int subg = blockIdx.y * 4 + ssub;
    const int b = ch >> 10, h = ch & 1023;
    const int g = h >> 6;

    float s = Sb[(size_t)subg * NCH + ch].x;
    size_t idx = ((size_t)b * T_ + (size_t)subg * SUB) * H_ + h;
    const float* fp = Fac + (size_t)(b * T_ + subg * SUB) * G_ + g;
    #pragma unroll 4
    for (int t = 0; t < SUB; ++t) {
        float c = bf2f(((const unsigned short*)Cb)[idx]) * fp[t * G_];
        float v = bf2f(((const unsigned short*)Vb)[idx]);
        s = logaddexp_f(s + c, v);
        float out = fexp2(fminf(s, 88.f) * LOG2Ef);  // finite, <= 1.7e38
        ((unsigned short*)Vb)[idx] = f2bf(out);
        idx += H_;
    }
}

// ---------------------------------------------------------------------------
extern "C" void kernel_launch(void* const* d_in, const int* in_sizes, int n_in,
                              void* d_out, int out_size, void* d_ws, size_t ws_size,
                              hipStream_t stream)
{
    const float* x   = (const float*)d_in[0];
    const float* h0  = (const float*)d_in[1];
    const float* Wz  = (const float*)d_in[2];
    const float* bz  = (const float*)d_in[3];
    const float* Wh  = (const float*)d_in[4];
    const float* bh  = (const float*)d_in[5];

    bf16_t* out = (bf16_t*)d_out;                                 // [B,T,H] bf16
    char*   ws  = (char*)d_ws;
    bf16_t* Cb  = (bf16_t*)ws;                                    // 33.5 MB raw lc0
    float2* Sb  = (float2*)(ws + (size_t)M_ * H_ * 2);            //  4.0 MB
    bf16_t* Xb  = (bf16_t*)((char*)Sb + (size_t)NSUB * NCH * 8);  // 33.5 MB
    bf16_t* Wzb = Xb + (size_t)M_ * DIN;                          //  2.0 MB
    bf16_t* Whb = Wzb + (size_t)H_ * DIN;                         //  2.0 MB
    float*  Nb  = (float*)(Whb + (size_t)H_ * DIN);               //  1.0 MB norms->fac

    cvt_all<<<NX8 / 256 + 2 * (NW8 / 256), 256, 0, stream>>>(x, Xb, Wz, Wzb, Wh, Whb);
    gemm_mfma<<<dim3(M_ / BM, H_ / BN), 256, 0, stream>>>(Xb, Wzb, bz, Whb, bh, Cb, out, Nb);
    fack<<<M_ / 256, 256, 0, stream>>>(Nb);
    scan_sum<<<dim3(NCH / 64, NSUB / 4), 256, 0, stream>>>(Cb, out, Nb, Sb);
    scan_mid<<<NCH / 256, 256, 0, stream>>>(Sb, h0);
    scan_out<<<dim3(NCH / 64, NSUB / 4), 256, 0, stream>>>(Cb, out, Nb, Sb);
}